// Round 9
// baseline (901.983 us; speedup 1.0000x reference)
//
#include <hip/hip_runtime.h>

// Round 9 = re-bench of round-8 proposal (round-8 attempt hit GPUAcquisitionTimeout,
// never measured). (a) bf16 feature cache in ws => row = 64B = ONE s_load_dwordx16,
// enabling a depth-2 scalar pipeline (2 rows in flight per lgkmcnt(0) drain)
// within the SGPR budget; halves random-fetch bytes. (b) nontemporal bucket
// stores in build_buckets (avoid L2 line-fill RMW on random 4B scatter).
// Walls measured in r7: conv = exposed random-fetch latency (one 128B row per
// wave in flight, ~240 cy/entry/CU, all pipes <17%); build ~230us random stores.

#define N_VOXELS 150000
#define NP 60000
#define NK 27
#define CIN 32
#define COUT 64
#define BN_EPS 1e-5f
#define NELEM (N_VOXELS * COUT)
#define NFEAT (N_VOXELS * CIN)

#define RVOX 64                                  // voxels per range (block)
#define RSHIFT 6
#define NR ((N_VOXELS + RVOX - 1) / RVOX)        // 2344 ranges
#define CAP 1024                                 // bucket cap (avg 691, +12 sigma)

// ws layout (int32 units):
//   [0 .. NR)            range counters
//   [4096 .. 4224)       BN stats (float): sum[64], sumsq[64]
//   [8192 .. +NR*CAP)    bucket lists (~9.6 MB)
//   [WS_FBF16 .. )       bf16 feature cache, N_VOXELS*32 ushort (~9.6 MB)
#define WS_CNT   0
#define WS_STATS 4096
#define WS_LIST  8192
#define WS_FBF16 (WS_LIST + NR * CAP)

typedef int v16i __attribute__((ext_vector_type(16)));

// ---------------------------------------------------------------------------
// Kernel 0: convert features f32 -> bf16 (RNE), sequential, ~29MB traffic.
// ---------------------------------------------------------------------------
__global__ __launch_bounds__(256) void cvt_bf16(
    const float* __restrict__ features, unsigned int* __restrict__ fbf16_u32)
{
    const int tid    = blockIdx.x * 256 + threadIdx.x;
    const int stride = gridDim.x * 256;
    const float4* f4 = reinterpret_cast<const float4*>(features);
    for (int i = tid; i < NFEAT / 4; i += stride) {
        float4 v = f4[i];
        unsigned int u0 = __float_as_uint(v.x), u1 = __float_as_uint(v.y);
        unsigned int u2 = __float_as_uint(v.z), u3 = __float_as_uint(v.w);
        u0 = (u0 + 0x7FFFu + ((u0 >> 16) & 1u)) >> 16;
        u1 = (u1 + 0x7FFFu + ((u1 >> 16) & 1u)) >> 16;
        u2 = (u2 + 0x7FFFu + ((u2 >> 16) & 1u)) >> 16;
        u3 = (u3 + 0x7FFFu + ((u3 >> 16) & 1u)) >> 16;
        fbf16_u32[i * 2]     = u0 | (u1 << 16);
        fbf16_u32[i * 2 + 1] = u2 | (u3 << 16);
    }
}

// ---------------------------------------------------------------------------
// Kernel 1: build range buckets. entry = (k<<24) | (vin<<6) | (vout & 63).
// Nontemporal store for the random 4B scatter.
// ---------------------------------------------------------------------------
__global__ __launch_bounds__(256) void build_buckets(
    const int* __restrict__ in_idx,
    const int* __restrict__ out_idx,
    int* __restrict__ ws)
{
    const int idx = blockIdx.x * 256 + threadIdx.x;
    if (idx >= NK * NP) return;
    const int k    = idx / NP;
    const int vout = out_idx[idx];
    const int vin  = in_idx[idx];
    const int r    = vout >> RSHIFT;
    const int slot = atomicAdd(&ws[WS_CNT + r], 1);
    if (slot < CAP)
        __builtin_nontemporal_store((k << 24) | (vin << RSHIFT) | (vout & (RVOX - 1)),
                                    &ws[WS_LIST + r * CAP + slot]);
}

// ---------------------------------------------------------------------------
// Kernel 2: gather conv per range, k-binned. Per iteration a wave handles TWO
// entries: both bf16 rows (64B each) are fetched with two s_load_dwordx16 in
// ONE asm block -> one lgkmcnt(0) drain covers both (MLP 2). Unpack bf16->f32
// on the SALU (shift/mask), 32 v_fmac vs f32 weight column (lane = cout),
// ds_add into LDS accum. Epilogue: relu(acc+bias) store + fused BN stats.
// ---------------------------------------------------------------------------
__global__ __launch_bounds__(256, 6) void conv_gather(
    const unsigned short* __restrict__ fbf16,
    const float* __restrict__ weight,
    const float* __restrict__ bias,
    const int* __restrict__ ws_i,
    float* __restrict__ out,
    float* __restrict__ stats)
{
    __shared__ float accum[RVOX * COUT];    // 16 KB
    __shared__ int   kbin[CAP];             // 4 KB
    __shared__ int   khist[NK];
    __shared__ int   koff[NK + 1];
    __shared__ int   kcur[NK];
    __shared__ float lsum[COUT];
    __shared__ float lsq[COUT];

    const int r    = blockIdx.x;
    const int tid  = threadIdx.x;
    const int lane = tid & 63;
    const int wid  = tid >> 6;

    int n = ws_i[WS_CNT + r];
    if (n > CAP) n = CAP;
    const int* list = ws_i + WS_LIST + (size_t)r * CAP;

    float4* acc4 = reinterpret_cast<float4*>(accum);
    for (int i = tid; i < RVOX * COUT / 4; i += 256) acc4[i] = float4{0.f, 0.f, 0.f, 0.f};
    if (tid < NK) khist[tid] = 0;
    if (tid < COUT) { lsum[tid] = 0.f; lsq[tid] = 0.f; }
    __syncthreads();

    for (int i = tid; i < n; i += 256) atomicAdd(&khist[list[i] >> 24], 1);
    __syncthreads();
    if (tid == 0) {
        int a = 0;
        for (int k = 0; k < NK; ++k) { koff[k] = a; kcur[k] = a; a += khist[k]; }
        koff[NK] = a;
    }
    __syncthreads();
    for (int i = tid; i < n; i += 256) {
        const int pk = list[i];
        kbin[atomicAdd(&kcur[pk >> 24], 1)] = pk;
    }
    __syncthreads();

    for (int k = 0; k < NK; ++k) {
        const int b0 = koff[k], b1 = koff[k + 1];
        if (b0 == b1) continue;

        // weight column for this lane's cout, resident in VGPRs (f32)
        float w[CIN];
        const float* wk = weight + k * (CIN * COUT) + lane;
#pragma unroll
        for (int c = 0; c < CIN; ++c) w[c] = wk[c * COUT];

        // each wave takes entry-pairs, interleaved by wave id
        for (int j0 = b0 + wid * 2; j0 < b1; j0 += 8) {
            const bool hasB = (j0 + 1 < b1);
            const int  jB   = hasB ? (j0 + 1) : j0;
            const int pkA = __builtin_amdgcn_readfirstlane(kbin[j0]);
            const int pkB = __builtin_amdgcn_readfirstlane(kbin[jB]);
            const int vinA = (pkA >> RSHIFT) & 0x3FFFF, lvA = pkA & (RVOX - 1);
            const int vinB = (pkB >> RSHIFT) & 0x3FFFF, lvB = pkB & (RVOX - 1);
            const unsigned short* rowA = fbf16 + (size_t)vinA * CIN;
            const unsigned short* rowB = fbf16 + (size_t)vinB * CIN;

            v16i ra, rb;
            asm volatile(
                "s_load_dwordx16 %0, %2, 0\n\t"
                "s_load_dwordx16 %1, %3, 0\n\t"
                "s_waitcnt lgkmcnt(0)"
                : "=&s"(ra), "=&s"(rb)
                : "s"(rowA), "s"(rowB));

            float accA = 0.f;
#pragma unroll
            for (int i = 0; i < 16; ++i) {
                const unsigned int s = (unsigned int)ra[i];
                accA = fmaf(__uint_as_float(s << 16),        w[2 * i],     accA);
                accA = fmaf(__uint_as_float(s & 0xFFFF0000u), w[2 * i + 1], accA);
            }
            atomicAdd(&accum[lvA * COUT + lane], accA);     // ds_add_f32

            if (hasB) {
                float accB = 0.f;
#pragma unroll
                for (int i = 0; i < 16; ++i) {
                    const unsigned int s = (unsigned int)rb[i];
                    accB = fmaf(__uint_as_float(s << 16),        w[2 * i],     accB);
                    accB = fmaf(__uint_as_float(s & 0xFFFF0000u), w[2 * i + 1], accB);
                }
                atomicAdd(&accum[lvB * COUT + lane], accB);
            }
        }
    }
    __syncthreads();

    // epilogue: y = relu(acc + bias), coalesced store, fused BN stats
    const int v0 = r * RVOX;
    const int nv = (N_VOXELS - v0 < RVOX) ? (N_VOXELS - v0) : RVOX;
    const float b = bias[lane];            // channel == tid&63 (stride 256)
    float rs = 0.f, rq = 0.f;
    for (int i = tid; i < nv * COUT; i += 256) {
        float y = accum[i] + b;
        y = fmaxf(y, 0.f);
        out[(size_t)v0 * COUT + i] = y;
        rs += y;
        rq += y * y;
    }
    atomicAdd(&lsum[lane], rs);
    atomicAdd(&lsq[lane], rq);
    __syncthreads();
    if (tid < COUT) atomicAdd(&stats[tid], lsum[tid]);
    else if (tid < 2 * COUT) atomicAdd(&stats[tid], lsq[tid - COUT]);
}

// ---------------------------------------------------------------------------
// Kernel 3: in-place BN apply on y (already ReLU'd), float4-vectorized.
// ---------------------------------------------------------------------------
__global__ __launch_bounds__(256) void bn_apply(
    float* __restrict__ buf,
    const float* __restrict__ stats,
    const float* __restrict__ gamma,
    const float* __restrict__ beta)
{
    const float inv_n = 1.f / (float)N_VOXELS;
    const int cg = (threadIdx.x & 15) * 4;
    float sc[4], sh[4];
#pragma unroll
    for (int j = 0; j < 4; ++j) {
        const int c = cg + j;
        const float mean = stats[c] * inv_n;
        const float var  = stats[COUT + c] * inv_n - mean * mean;
        sc[j] = gamma[c] * rsqrtf(var + BN_EPS);
        sh[j] = beta[c] - mean * sc[j];
    }
    const int tid    = blockIdx.x * 256 + threadIdx.x;
    const int stride = gridDim.x * 256;
    float4* buf4 = reinterpret_cast<float4*>(buf);
    for (int i = tid; i < NELEM / 4; i += stride) {
        float4 y = buf4[i];
        y.x = fmaf(y.x, sc[0], sh[0]);
        y.y = fmaf(y.y, sc[1], sh[1]);
        y.z = fmaf(y.z, sc[2], sh[2]);
        y.w = fmaf(y.w, sc[3], sh[3]);
        buf4[i] = y;
    }
}

extern "C" void kernel_launch(void* const* d_in, const int* in_sizes, int n_in,
                              void* d_out, int out_size, void* d_ws, size_t ws_size,
                              hipStream_t stream) {
    const float* features = (const float*)d_in[0];
    const int*   in_idx   = (const int*)d_in[1];
    const int*   out_idx  = (const int*)d_in[2];
    const float* weight   = (const float*)d_in[3];
    const float* bias     = (const float*)d_in[4];
    const float* gamma    = (const float*)d_in[5];
    const float* beta     = (const float*)d_in[6];
    float* out   = (float*)d_out;
    int*   ws    = (int*)d_ws;
    float* stats = (float*)d_ws + WS_STATS;
    unsigned int*   fbf16_u32 = (unsigned int*)(ws + WS_FBF16);
    const unsigned short* fbf16 = (const unsigned short*)(ws + WS_FBF16);

    // zero counters + stats (first 32 KB); bucket payload needs no init
    hipMemsetAsync(d_ws, 0, (size_t)WS_LIST * sizeof(int), stream);

    cvt_bf16<<<1024, 256, 0, stream>>>(features, fbf16_u32);

    build_buckets<<<(NK * NP + 255) / 256, 256, 0, stream>>>(in_idx, out_idx, ws);

    conv_gather<<<NR, 256, 0, stream>>>(fbf16, weight, bias, ws, out, stats);

    bn_apply<<<2048, 256, 0, stream>>>(out, stats, gamma, beta);
}